// Round 6
// baseline (1731.070 us; speedup 1.0000x reference)
//
#include <hip/hip_runtime.h>

// ---------------- types / helpers ----------------
typedef unsigned short u16;
typedef u16    u16x8 __attribute__((ext_vector_type(8)));
typedef __bf16 bf16x8 __attribute__((ext_vector_type(8)));
typedef float  f32x4 __attribute__((ext_vector_type(4)));

#define BS  512
#define DIM 1024
#define HID 2048
#define NSTEPS 20

__device__ __forceinline__ u16 f2b(float x) {             // f32 -> bf16 bits, RNE
    unsigned u = __float_as_uint(x);
    return (u16)((u + 0x7FFFu + ((u >> 16) & 1u)) >> 16);
}
__device__ __forceinline__ float b2f(u16 h) { return __uint_as_float(((unsigned)h) << 16); }

__device__ __forceinline__ float fast_tanh(float x) {
    float ax = fabsf(x);
    float e  = __expf(2.0f * ax);
    float t  = 1.0f - 2.0f / (e + 1.0f);
    return copysignf(t, x);
}

#define MFMA16(a, b, c) __builtin_amdgcn_mfma_f32_16x16x32_bf16( \
    __builtin_bit_cast(bf16x8, (a)), __builtin_bit_cast(bf16x8, (b)), (c), 0, 0, 0)

// Frag-packed layout: chunk = 1KB = [64 lanes][8 bf16] holding a 16(outer)x32(k)
// tile; lane l -> outer (l&15), k-offset (l>>4)*8. Array: [frag][kstep][chunk].

__device__ __forceinline__ void glds16(const u16* g, u16* s) {
    __builtin_amdgcn_global_load_lds(
        (const __attribute__((address_space(1))) void*)g,
        (__attribute__((address_space(3))) void*)s, 16, 0, 0);
}

// ---------------- prep kernels (verified round-2/4 runs) ----------------
__global__ __launch_bounds__(256) void pack_w(const float* __restrict__ W, int K, int N,
                                              u16* __restrict__ Dh, u16* __restrict__ Dl) {
    __shared__ float tile[32][65];
    const int t  = threadIdx.x;
    const int n0 = blockIdx.x * 64;
    const int k0 = blockIdx.y * 32;
#pragma unroll
    for (int i = 0; i < 8; ++i) {
        int idx = i * 256 + t;
        int ky = idx >> 6, nx = idx & 63;
        tile[ky][nx] = W[(size_t)(k0 + ky) * N + n0 + nx];
    }
    __syncthreads();
    const int lane = t & 63, nfl = t >> 6;
    const int r = lane & 15, q = lane >> 4;
    const int nl = nfl * 16 + r;
    u16x8 vh, vl;
#pragma unroll
    for (int j = 0; j < 8; ++j) {
        float v = tile[q * 8 + j][nl];
        u16 h = f2b(v);
        vh[j] = h;
        vl[j] = f2b(v - b2f(h));
    }
    const int KS = K >> 5;
    const size_t nf  = (size_t)(n0 >> 4) + nfl;
    const size_t off = (nf * KS + (k0 >> 5)) * 512 + lane * 8;
    *(u16x8*)(Dh + off) = vh;
    *(u16x8*)(Dl + off) = vl;
}

__global__ __launch_bounds__(256) void pack_z(const float* __restrict__ z0,
                                              float* __restrict__ Zf,
                                              u16* __restrict__ Zh, u16* __restrict__ Zl) {
    const int gid  = blockIdx.x * 256 + threadIdx.x;  // 65536 total
    const int lane = gid & 63;
    const int cidx = gid >> 6;                        // 0..1023
    const int ks = cidx & 31;
    const int mf = cidx >> 5;                         // 0..31
    const int r = lane & 15, q = lane >> 4;
    const int row = mf * 16 + r;
    const int col = ks * 32 + q * 8;
    const float* src = z0 + (size_t)row * DIM + col;
    f32x4 a = *(const f32x4*)src;
    f32x4 b = *(const f32x4*)(src + 4);
    u16x8 vh, vl;
#pragma unroll
    for (int j = 0; j < 4; ++j) {
        u16 h = f2b(a[j]); vh[j] = h; vl[j] = f2b(a[j] - b2f(h));
        u16 h2 = f2b(b[j]); vh[4 + j] = h2; vl[4 + j] = f2b(b[j] - b2f(h2));
    }
    *(f32x4*)(Zf + (size_t)row * DIM + col)     = a;
    *(f32x4*)(Zf + (size_t)row * DIM + col + 4) = b;
    const size_t off = ((size_t)mf * 32 + ks) * 512 + lane * 8;
    *(u16x8*)(Zh + off) = vh;
    *(u16x8*)(Zl + off) = vl;
}

// ---------------- single-wave LDS-staged GEMM ----------------
// One 64-lane wave per block computes a (MF*16) x (NF*16) tile.
// K-loop: double-buffered global_load_lds of frag-packed chunks, counted vmcnt,
// NO barriers (single wave). 3-term split-bf16 MFMA.
// EPI 1: H = tanh(acc+bias+ti*wt) -> Oh/Ol A-frag-packed ([mf][KSo][512])
// EPI 2: zn = Zin + hseg*(acc+bias) -> Fout f32 row-major (+ packed Oh/Ol)
template <int MF, int NF, int KSc, int KSo, int EPI>
__global__ __launch_bounds__(64) void gemm_1w(
    const u16* __restrict__ Ah, const u16* __restrict__ Al,
    const u16* __restrict__ Bh, const u16* __restrict__ Bl,
    const float* __restrict__ bias, const float* __restrict__ wvec,
    const float* __restrict__ t, int step,
    const float* __restrict__ Zin, float* __restrict__ Fout,
    u16* __restrict__ Oh, u16* __restrict__ Ol, int wsplit) {

    constexpr int NCH = (MF + NF) * 2;          // staged chunks per K-step
    __shared__ __align__(16) u16   sb[2][NCH][512];           // double-buffered staging
    __shared__ __align__(16) float epi[MF * 16][NF * 16 + 4]; // epilogue transpose

    const int l   = threadIdx.x;                // lane 0..63
    const int nwg = gridDim.x;
    const int bid = blockIdx.x;
    const int swz = (bid & 7) * (nwg >> 3) + (bid >> 3);  // bijective, XCD-contiguous bn
    constexpr int BM = BS / (MF * 16);          // 8
    const int bm = swz % BM;
    const int bn = swz / BM;

    const u16* pAh = Ah + ((size_t)(bm * MF) * KSc) * 512 + l * 8;
    const u16* pAl = Al + ((size_t)(bm * MF) * KSc) * 512 + l * 8;
    const u16* pBh = Bh + ((size_t)(bn * NF) * KSc) * 512 + l * 8;
    const u16* pBl = Bl + ((size_t)(bn * NF) * KSc) * 512 + l * 8;

    // time-step scalars (complete before staging so vmcnt counts stay exact)
    const int   seg  = step >> 1, sub = step & 1;
    const float t0   = t[seg], t1 = t[seg + 1];
    const float hseg = 0.5f * (t1 - t0);
    const float ti   = t0 + hseg * (float)sub;
    asm volatile("s_waitcnt vmcnt(0) lgkmcnt(0)" ::: "memory");

    auto STAGE = [&](int k, int nb) {
#pragma unroll
        for (int c = 0; c < MF; ++c) {
            glds16(pAh + ((size_t)c * KSc + k) * 512, &sb[nb][c][0]);
            glds16(pAl + ((size_t)c * KSc + k) * 512, &sb[nb][MF + c][0]);
        }
#pragma unroll
        for (int c = 0; c < NF; ++c) {
            glds16(pBh + ((size_t)c * KSc + k) * 512, &sb[nb][2 * MF + c][0]);
            glds16(pBl + ((size_t)c * KSc + k) * 512, &sb[nb][2 * MF + NF + c][0]);
        }
    };

    f32x4 acc[MF][NF] = {};

    auto COMPUTE = [&](int cur) {
        u16x8 ah[MF], al[MF], bh[NF], bl[NF];
#pragma unroll
        for (int mi = 0; mi < MF; ++mi) {
            ah[mi] = *(const u16x8*)&sb[cur][mi][l * 8];
            al[mi] = *(const u16x8*)&sb[cur][MF + mi][l * 8];
        }
#pragma unroll
        for (int ni = 0; ni < NF; ++ni) {
            bh[ni] = *(const u16x8*)&sb[cur][2 * MF + ni][l * 8];
            bl[ni] = *(const u16x8*)&sb[cur][2 * MF + NF + ni][l * 8];
        }
#pragma unroll
        for (int mi = 0; mi < MF; ++mi)
#pragma unroll
            for (int ni = 0; ni < NF; ++ni) {
                acc[mi][ni] = MFMA16(ah[mi], bh[ni], acc[mi][ni]);
                acc[mi][ni] = MFMA16(ah[mi], bl[ni], acc[mi][ni]);
                acc[mi][ni] = MFMA16(al[mi], bh[ni], acc[mi][ni]);
            }
    };

    STAGE(0, 0);
    for (int k = 0; k < KSc - 1; ++k) {
        // ds_reads of the buffer about to be overwritten must be consumed (WAR guard)
        asm volatile("s_waitcnt lgkmcnt(0)" ::: "memory");
        STAGE(k + 1, (k + 1) & 1);
        asm volatile("s_waitcnt vmcnt(%0)" :: "i"(NCH) : "memory");  // buf[k&1] staged
        COMPUTE(k & 1);
    }
    asm volatile("s_waitcnt vmcnt(0)" ::: "memory");
    COMPUTE((KSc - 1) & 1);

    // ---- epilogue: transpose C-frags through LDS (single wave, no barrier) ----
    const int r = l & 15, q = l >> 4;
#pragma unroll
    for (int mi = 0; mi < MF; ++mi)
#pragma unroll
        for (int ni = 0; ni < NF; ++ni)
#pragma unroll
            for (int j = 0; j < 4; ++j)
                epi[mi * 16 + q * 4 + j][ni * 16 + r] = acc[mi][ni][j];

#pragma unroll
    for (int mi = 0; mi < MF; ++mi)
#pragma unroll
        for (int kc = 0; kc < NF / 2; ++kc) {
            const int c0 = bn * (NF * 16) + kc * 32 + q * 8;   // global n base, lane
            f32x4 v0 = *(const f32x4*)&epi[mi * 16 + r][kc * 32 + q * 8];
            f32x4 v1 = *(const f32x4*)&epi[mi * 16 + r][kc * 32 + q * 8 + 4];
            float v[8];
#pragma unroll
            for (int j = 0; j < 4; ++j) { v[j] = v0[j]; v[4 + j] = v1[j]; }

            const int    mfg = bm * MF + mi;
            const int    kch = bn * (NF / 2) + kc;
            const size_t off = ((size_t)mfg * KSo + kch) * 512 + l * 8;

            if constexpr (EPI == 1) {
                u16x8 vh, vl;
#pragma unroll
                for (int j = 0; j < 8; ++j) {
                    float u  = v[j] + bias[c0 + j] + ti * wvec[c0 + j];
                    float tv = fast_tanh(u);
                    u16 hb = f2b(tv);
                    vh[j] = hb;
                    vl[j] = f2b(tv - b2f(hb));
                }
                *(u16x8*)(Oh + off) = vh;
                *(u16x8*)(Ol + off) = vl;
            } else {
                constexpr int NT = KSo * 32;               // output row length
                const int    rg  = bm * (MF * 16) + mi * 16 + r;
                const float* zp  = Zin + (size_t)rg * NT + c0;
                f32x4 z0v = *(const f32x4*)zp;
                f32x4 z1v = *(const f32x4*)(zp + 4);
                float zn[8];
#pragma unroll
                for (int j = 0; j < 8; ++j) {
                    float f  = v[j] + bias[c0 + j];
                    float zi = (j < 4) ? z0v[j] : z1v[j - 4];
                    zn[j] = zi + hseg * f;
                }
                f32x4 o0, o1;
#pragma unroll
                for (int j = 0; j < 4; ++j) { o0[j] = zn[j]; o1[j] = zn[4 + j]; }
                *(f32x4*)(Fout + (size_t)rg * NT + c0)     = o0;
                *(f32x4*)(Fout + (size_t)rg * NT + c0 + 4) = o1;
                if (wsplit) {
                    u16x8 vh, vl;
#pragma unroll
                    for (int j = 0; j < 8; ++j) {
                        u16 hb = f2b(zn[j]);
                        vh[j] = hb;
                        vl[j] = f2b(zn[j] - b2f(hb));
                    }
                    *(u16x8*)(Oh + off) = vh;
                    *(u16x8*)(Ol + off) = vl;
                }
            }
        }
}

// ---------------- launch ----------------
extern "C" void kernel_launch(void* const* d_in, const int* in_sizes, int n_in,
                              void* d_out, int out_size, void* d_ws, size_t ws_size,
                              hipStream_t stream) {
    const float* z0 = (const float*)d_in[0];
    const float* t  = (const float*)d_in[1];
    const float* W1 = (const float*)d_in[2];
    const float* b1 = (const float*)d_in[3];
    const float* wt = (const float*)d_in[4];
    const float* W2 = (const float*)d_in[5];
    const float* b2 = (const float*)d_in[6];

    char* ws = (char*)d_ws;
    float* Zf  = (float*)(ws);                    // 2 MB   512x1024 f32
    u16*   Zh  = (u16*)(ws + (2u  << 20));        // 1 MB   packed [32][32][512]
    u16*   Zl  = (u16*)(ws + (3u  << 20));        // 1 MB
    u16*   Hh  = (u16*)(ws + (4u  << 20));        // 2 MB   packed [32][64][512]
    u16*   Hl  = (u16*)(ws + (6u  << 20));        // 2 MB
    u16*   W1h = (u16*)(ws + (8u  << 20));        // 4 MB   packed [128][32][512]
    u16*   W1l = (u16*)(ws + (12u << 20));        // 4 MB
    u16*   W2h = (u16*)(ws + (16u << 20));        // 4 MB   packed [64][64][512]
    u16*   W2l = (u16*)(ws + (20u << 20));        // 4 MB

    pack_w<<<dim3(HID / 64, DIM / 32), 256, 0, stream>>>(W1, DIM, HID, W1h, W1l);
    pack_w<<<dim3(DIM / 64, HID / 32), 256, 0, stream>>>(W2, HID, DIM, W2h, W2l);
    pack_z<<<256, 256, 0, stream>>>(z0, Zf, Zh, Zl);

    float* out = (float*)d_out;
    for (int step = 0; step < NSTEPS; ++step) {
        // H = tanh(Z @ W1 + b1 + ti*wt)   (512x2048, K=1024): 64x64 tiles, grid 256
        gemm_1w<4, 4, 32, 64, 1><<<256, 64, 0, stream>>>(
            Zh, Zl, W1h, W1l, b1, wt, t, step,
            nullptr, nullptr, Hh, Hl, 1);
        // Znew = Z + h*(H @ W2 + b2)      (512x1024, K=2048): 64x32 tiles, grid 256
        const bool last = (step == NSTEPS - 1);
        gemm_1w<4, 2, 64, 32, 2><<<256, 64, 0, stream>>>(
            Hh, Hl, W2h, W2l, b2, nullptr, t, step,
            Zf, last ? out : Zf, Zh, Zl, last ? 0 : 1);
    }
}

// Round 7
// 762.762 us; speedup vs baseline: 2.2695x; 2.2695x over previous
//
#include <hip/hip_runtime.h>

// ---------------- types / helpers ----------------
typedef unsigned short u16;
typedef u16    u16x8 __attribute__((ext_vector_type(8)));
typedef __bf16 bf16x8 __attribute__((ext_vector_type(8)));
typedef float  f32x4 __attribute__((ext_vector_type(4)));

#define BS  512
#define DIM 1024
#define HID 2048
#define NSTEPS 20

__device__ __forceinline__ u16 f2b(float x) {             // f32 -> bf16 bits, RNE
    unsigned u = __float_as_uint(x);
    return (u16)((u + 0x7FFFu + ((u >> 16) & 1u)) >> 16);
}
__device__ __forceinline__ float b2f(u16 h) { return __uint_as_float(((unsigned)h) << 16); }

__device__ __forceinline__ float fast_tanh(float x) {
    float ax = fabsf(x);
    float e  = __expf(2.0f * ax);
    float t  = 1.0f - 2.0f / (e + 1.0f);
    return copysignf(t, x);
}

#define MFMA16(a, b, c) __builtin_amdgcn_mfma_f32_16x16x32_bf16( \
    __builtin_bit_cast(bf16x8, (a)), __builtin_bit_cast(bf16x8, (b)), (c), 0, 0, 0)

// Frag-packed layout: chunk = 1KB = [64 lanes][8 bf16] holding a 16(outer)x32(k)
// tile; lane l -> outer (l&15), k-offset (l>>4)*8. Array: [frag][kstep][chunk].

__device__ __forceinline__ void glds16(const u16* g, u16* s) {
    __builtin_amdgcn_global_load_lds(
        (const __attribute__((address_space(1))) void*)g,
        (__attribute__((address_space(3))) void*)s, 16, 0, 0);
}

// ---------------- prep kernels (verified in two passing runs) ----------------
__global__ __launch_bounds__(256) void pack_w(const float* __restrict__ W, int K, int N,
                                              u16* __restrict__ Dh, u16* __restrict__ Dl) {
    __shared__ float tile[32][65];
    const int t  = threadIdx.x;
    const int n0 = blockIdx.x * 64;
    const int k0 = blockIdx.y * 32;
#pragma unroll
    for (int i = 0; i < 8; ++i) {
        int idx = i * 256 + t;
        int ky = idx >> 6, nx = idx & 63;
        tile[ky][nx] = W[(size_t)(k0 + ky) * N + n0 + nx];
    }
    __syncthreads();
    const int lane = t & 63, nfl = t >> 6;
    const int r = lane & 15, q = lane >> 4;
    const int nl = nfl * 16 + r;
    u16x8 vh, vl;
#pragma unroll
    for (int j = 0; j < 8; ++j) {
        float v = tile[q * 8 + j][nl];
        u16 h = f2b(v);
        vh[j] = h;
        vl[j] = f2b(v - b2f(h));
    }
    const int KS = K >> 5;
    const size_t nf  = (size_t)(n0 >> 4) + nfl;
    const size_t off = (nf * KS + (k0 >> 5)) * 512 + lane * 8;
    *(u16x8*)(Dh + off) = vh;
    *(u16x8*)(Dl + off) = vl;
}

__global__ __launch_bounds__(256) void pack_z(const float* __restrict__ z0,
                                              float* __restrict__ Zf,
                                              u16* __restrict__ Zh, u16* __restrict__ Zl) {
    const int gid  = blockIdx.x * 256 + threadIdx.x;  // 65536 total
    const int lane = gid & 63;
    const int cidx = gid >> 6;                        // 0..1023
    const int ks = cidx & 31;
    const int mf = cidx >> 5;                         // 0..31
    const int r = lane & 15, q = lane >> 4;
    const int row = mf * 16 + r;
    const int col = ks * 32 + q * 8;
    const float* src = z0 + (size_t)row * DIM + col;
    f32x4 a = *(const f32x4*)src;
    f32x4 b = *(const f32x4*)(src + 4);
    u16x8 vh, vl;
#pragma unroll
    for (int j = 0; j < 4; ++j) {
        u16 h = f2b(a[j]); vh[j] = h; vl[j] = f2b(a[j] - b2f(h));
        u16 h2 = f2b(b[j]); vh[4 + j] = h2; vl[4 + j] = f2b(b[j] - b2f(h2));
    }
    *(f32x4*)(Zf + (size_t)row * DIM + col)     = a;
    *(f32x4*)(Zf + (size_t)row * DIM + col + 4) = b;
    const size_t off = ((size_t)mf * 32 + ks) * 512 + lane * 8;
    *(u16x8*)(Zh + off) = vh;
    *(u16x8*)(Zl + off) = vl;
}

// ---------------- 4-wave 2-phase LDS-staged GEMM ----------------
// Block: 256 thr / 4 waves (2x2). Tile: (MFT*16) x (NFT*16). Wave tile:
// (MFT/2*16) x (NFT/2*16). K-loop: each wave stages CPW=NCH/4 chunks via
// global_load_lds, counted vmcnt (never 0 in loop), raw s_barriers (T3-min).
// EPI 1: H = tanh(acc+bias+ti*wt) -> Oh/Ol A-frag-packed ([mf][KSo][512])
// EPI 2: zn = Zin + hseg*(acc+bias) -> Fout f32 row-major (+ packed Oh/Ol)
template <int MFT, int NFT, int KSc, int KSo, int EPI>
__global__ __launch_bounds__(256) void gemm_mw(
    const u16* __restrict__ Ah, const u16* __restrict__ Al,
    const u16* __restrict__ Bh, const u16* __restrict__ Bl,
    const float* __restrict__ bias, const float* __restrict__ wvec,
    const float* __restrict__ t, int step,
    const float* __restrict__ Zin, float* __restrict__ Fout,
    u16* __restrict__ Oh, u16* __restrict__ Ol, int wsplit) {

    constexpr int NCH = (MFT + NFT) * 2;      // chunks per K-step (A hi/lo + B hi/lo)
    constexpr int CPW = NCH / 4;              // chunks staged per wave
    constexpr int MFW = MFT / 2, NFW = NFT / 2;
    __shared__ __align__(16) u16 sb[2][NCH][512];   // double-buffered staging

    const int tid = threadIdx.x;
    const int l   = tid & 63;
    const int w   = tid >> 6;                 // wave 0..3
    const int wm  = w >> 1, wn = w & 1;

    const int nwg = gridDim.x;
    const int bid = blockIdx.x;
    const int swz = (bid & 7) * (nwg >> 3) + (bid >> 3);  // bijective XCD swizzle
    constexpr int BM = BS / (MFT * 16);
    const int bm = swz % BM;
    const int bn = swz / BM;

    const u16* pAh = Ah + ((size_t)(bm * MFT) * KSc) * 512 + l * 8;
    const u16* pAl = Al + ((size_t)(bm * MFT) * KSc) * 512 + l * 8;
    const u16* pBh = Bh + ((size_t)(bn * NFT) * KSc) * 512 + l * 8;
    const u16* pBl = Bl + ((size_t)(bn * NFT) * KSc) * 512 + l * 8;

    // per-wave staging assignments (computed once; compile-time indexed)
    const u16* csrc[CPW];
    u16*       cd0[CPW];
    u16*       cd1[CPW];
#pragma unroll
    for (int i = 0; i < CPW; ++i) {
        const int c = w * CPW + i;
        const u16* s;
        if      (c < MFT)           s = pAh + (size_t)c * KSc * 512;
        else if (c < 2 * MFT)       s = pAl + (size_t)(c - MFT) * KSc * 512;
        else if (c < 2 * MFT + NFT) s = pBh + (size_t)(c - 2 * MFT) * KSc * 512;
        else                        s = pBl + (size_t)(c - 2 * MFT - NFT) * KSc * 512;
        csrc[i] = s;
        cd0[i]  = &sb[0][c][0];
        cd1[i]  = &sb[1][c][0];
    }

    // time-step scalars
    const int   seg  = step >> 1, sub = step & 1;
    const float t0   = t[seg], t1 = t[seg + 1];
    const float hseg = 0.5f * (t1 - t0);
    const float ti   = t0 + hseg * (float)sub;

    f32x4 acc[MFW][NFW] = {};

    auto STAGE = [&](int k, int nb) {
#pragma unroll
        for (int i = 0; i < CPW; ++i)
            glds16(csrc[i] + (size_t)k * 512, nb ? cd1[i] : cd0[i]);
    };

    auto COMPUTE = [&](int cur) {
        const u16* base = &sb[cur][0][0];
        u16x8 ah[MFW], al[MFW], bh[NFW], bl[NFW];
#pragma unroll
        for (int mi = 0; mi < MFW; ++mi) {
            ah[mi] = *(const u16x8*)(base + (size_t)(wm * MFW + mi) * 512 + l * 8);
            al[mi] = *(const u16x8*)(base + (size_t)(MFT + wm * MFW + mi) * 512 + l * 8);
        }
#pragma unroll
        for (int ni = 0; ni < NFW; ++ni) {
            bh[ni] = *(const u16x8*)(base + (size_t)(2 * MFT + wn * NFW + ni) * 512 + l * 8);
            bl[ni] = *(const u16x8*)(base + (size_t)(2 * MFT + NFT + wn * NFW + ni) * 512 + l * 8);
        }
#pragma unroll
        for (int mi = 0; mi < MFW; ++mi)
#pragma unroll
            for (int ni = 0; ni < NFW; ++ni) {
                acc[mi][ni] = MFMA16(ah[mi], bh[ni], acc[mi][ni]);
                acc[mi][ni] = MFMA16(ah[mi], bl[ni], acc[mi][ni]);
                acc[mi][ni] = MFMA16(al[mi], bh[ni], acc[mi][ni]);
            }
    };

    asm volatile("s_waitcnt vmcnt(0) lgkmcnt(0)" ::: "memory");
    STAGE(0, 0);
    for (int k = 0; k < KSc - 1; ++k) {
        STAGE(k + 1, (k + 1) & 1);                          // next tile in flight
        asm volatile("s_waitcnt vmcnt(%0)" :: "i"(CPW) : "memory");  // my k-loads done
        __builtin_amdgcn_s_barrier();                       // all waves: buf[k] ready
        COMPUTE(k & 1);
        __builtin_amdgcn_s_barrier();                       // buf[k] free for overwrite
    }
    asm volatile("s_waitcnt vmcnt(0)" ::: "memory");
    __builtin_amdgcn_s_barrier();
    COMPUTE((KSc - 1) & 1);
    __syncthreads();                                        // full drain before LDS reuse

    // ---- epilogue: transpose C-frags through reused LDS ----
    float* epi = reinterpret_cast<float*>(&sb[0][0][0]);    // [MFT*16][EW]
    constexpr int EW = NFT * 16 + 4;
    const int r = l & 15, q = l >> 4;
#pragma unroll
    for (int mi = 0; mi < MFW; ++mi)
#pragma unroll
        for (int ni = 0; ni < NFW; ++ni)
#pragma unroll
            for (int j = 0; j < 4; ++j)
                epi[(wm * MFW * 16 + mi * 16 + q * 4 + j) * EW
                    + wn * NFW * 16 + ni * 16 + r] = acc[mi][ni][j];
    __syncthreads();

    constexpr int PPW = (MFT * (NFT / 2)) / 4;   // (row-slice, col-chunk) pairs per wave
#pragma unroll
    for (int pi = 0; pi < PPW; ++pi) {
        const int p  = w * PPW + pi;
        const int rs = p / (NFT / 2);
        const int kc = p % (NFT / 2);
        const int c0 = bn * (NFT * 16) + kc * 32 + q * 8;   // global col base for lane
        f32x4 v0 = *(const f32x4*)&epi[(rs * 16 + r) * EW + kc * 32 + q * 8];
        f32x4 v1 = *(const f32x4*)&epi[(rs * 16 + r) * EW + kc * 32 + q * 8 + 4];
        float v[8];
#pragma unroll
        for (int j = 0; j < 4; ++j) { v[j] = v0[j]; v[4 + j] = v1[j]; }

        const int    mfg = bm * MFT + rs;
        const int    kch = bn * (NFT / 2) + kc;
        const size_t off = ((size_t)mfg * KSo + kch) * 512 + l * 8;

        if constexpr (EPI == 1) {
            u16x8 vh, vl;
#pragma unroll
            for (int j = 0; j < 8; ++j) {
                float u  = v[j] + bias[c0 + j] + ti * wvec[c0 + j];
                float tv = fast_tanh(u);
                u16 hb = f2b(tv);
                vh[j] = hb;
                vl[j] = f2b(tv - b2f(hb));
            }
            *(u16x8*)(Oh + off) = vh;
            *(u16x8*)(Ol + off) = vl;
        } else {
            constexpr int NT = KSo * 32;               // output row length
            const int    rg  = bm * (MFT * 16) + rs * 16 + r;
            const float* zp  = Zin + (size_t)rg * NT + c0;
            f32x4 z0v = *(const f32x4*)zp;
            f32x4 z1v = *(const f32x4*)(zp + 4);
            float zn[8];
#pragma unroll
            for (int j = 0; j < 8; ++j) {
                float f  = v[j] + bias[c0 + j];
                float zi = (j < 4) ? z0v[j] : z1v[j - 4];
                zn[j] = zi + hseg * f;
            }
            f32x4 o0, o1;
#pragma unroll
            for (int j = 0; j < 4; ++j) { o0[j] = zn[j]; o1[j] = zn[4 + j]; }
            *(f32x4*)(Fout + (size_t)rg * NT + c0)     = o0;
            *(f32x4*)(Fout + (size_t)rg * NT + c0 + 4) = o1;
            if (wsplit) {
                u16x8 vh, vl;
#pragma unroll
                for (int j = 0; j < 8; ++j) {
                    u16 hb = f2b(zn[j]);
                    vh[j] = hb;
                    vl[j] = f2b(zn[j] - b2f(hb));
                }
                *(u16x8*)(Oh + off) = vh;
                *(u16x8*)(Ol + off) = vl;
            }
        }
    }
}

// ---------------- launch ----------------
extern "C" void kernel_launch(void* const* d_in, const int* in_sizes, int n_in,
                              void* d_out, int out_size, void* d_ws, size_t ws_size,
                              hipStream_t stream) {
    const float* z0 = (const float*)d_in[0];
    const float* t  = (const float*)d_in[1];
    const float* W1 = (const float*)d_in[2];
    const float* b1 = (const float*)d_in[3];
    const float* wt = (const float*)d_in[4];
    const float* W2 = (const float*)d_in[5];
    const float* b2 = (const float*)d_in[6];

    char* ws = (char*)d_ws;
    float* Zf  = (float*)(ws);                    // 2 MB   512x1024 f32
    u16*   Zh  = (u16*)(ws + (2u  << 20));        // 1 MB   packed [32][32][512]
    u16*   Zl  = (u16*)(ws + (3u  << 20));        // 1 MB
    u16*   Hh  = (u16*)(ws + (4u  << 20));        // 2 MB   packed [32][64][512]
    u16*   Hl  = (u16*)(ws + (6u  << 20));        // 2 MB
    u16*   W1h = (u16*)(ws + (8u  << 20));        // 4 MB   packed [128][32][512]
    u16*   W1l = (u16*)(ws + (12u << 20));        // 4 MB
    u16*   W2h = (u16*)(ws + (16u << 20));        // 4 MB   packed [64][64][512]
    u16*   W2l = (u16*)(ws + (20u << 20));        // 4 MB

    pack_w<<<dim3(HID / 64, DIM / 32), 256, 0, stream>>>(W1, DIM, HID, W1h, W1l);
    pack_w<<<dim3(DIM / 64, HID / 32), 256, 0, stream>>>(W2, HID, DIM, W2h, W2l);
    pack_z<<<256, 256, 0, stream>>>(z0, Zf, Zh, Zl);

    float* out = (float*)d_out;
    for (int step = 0; step < NSTEPS; ++step) {
        // H = tanh(Z @ W1 + b1 + ti*wt)   (512x2048, K=1024): 64x64 tiles, grid 256
        gemm_mw<4, 4, 32, 64, 1><<<256, 256, 0, stream>>>(
            Zh, Zl, W1h, W1l, b1, wt, t, step,
            nullptr, nullptr, Hh, Hl, 1);
        // Znew = Z + h*(H @ W2 + b2)      (512x1024, K=2048): 32x64 tiles, grid 256
        const bool last = (step == NSTEPS - 1);
        gemm_mw<2, 4, 64, 32, 2><<<256, 256, 0, stream>>>(
            Hh, Hl, W2h, W2l, b2, nullptr, t, step,
            Zf, last ? out : Zf, Zh, Zl, last ? 0 : 1);
    }
}

// Round 11
// 732.062 us; speedup vs baseline: 2.3646x; 1.0419x over previous
//
#include <hip/hip_runtime.h>

// ---------------- types / helpers ----------------
typedef unsigned short u16;
typedef u16    u16x8 __attribute__((ext_vector_type(8)));
typedef __bf16 bf16x8 __attribute__((ext_vector_type(8)));
typedef float  f32x4 __attribute__((ext_vector_type(4)));

#define BS  512
#define DIM 1024
#define HID 2048
#define NSTEPS 20

__device__ __forceinline__ u16 f2b(float x) {             // f32 -> bf16 bits, RNE
    unsigned u = __float_as_uint(x);
    return (u16)((u + 0x7FFFu + ((u >> 16) & 1u)) >> 16);
}
__device__ __forceinline__ float b2f(u16 h) { return __uint_as_float(((unsigned)h) << 16); }

__device__ __forceinline__ float fast_tanh(float x) {
    float ax = fabsf(x);
    float e  = __expf(2.0f * ax);
    float t  = 1.0f - 2.0f / (e + 1.0f);
    return copysignf(t, x);
}

#define MFMA16(a, b, c) __builtin_amdgcn_mfma_f32_16x16x32_bf16( \
    __builtin_bit_cast(bf16x8, (a)), __builtin_bit_cast(bf16x8, (b)), (c), 0, 0, 0)

// Frag-packed layout: chunk = 1KB = [64 lanes][8 bf16] holding a 16(outer)x32(k)
// tile; lane l -> outer (l&15), k-offset (l>>4)*8. Array: [frag][kstep][chunk].

__device__ __forceinline__ void glds16(const u16* g, u16* s) {
    __builtin_amdgcn_global_load_lds(
        (const __attribute__((address_space(1))) void*)g,
        (__attribute__((address_space(3))) void*)s, 16, 0, 0);
}

// ---------------- prep kernels (verified in three passing runs) ----------------
__global__ __launch_bounds__(256) void pack_w(const float* __restrict__ W, int K, int N,
                                              u16* __restrict__ Dh, u16* __restrict__ Dl) {
    __shared__ float tile[32][65];
    const int t  = threadIdx.x;
    const int n0 = blockIdx.x * 64;
    const int k0 = blockIdx.y * 32;
#pragma unroll
    for (int i = 0; i < 8; ++i) {
        int idx = i * 256 + t;
        int ky = idx >> 6, nx = idx & 63;
        tile[ky][nx] = W[(size_t)(k0 + ky) * N + n0 + nx];
    }
    __syncthreads();
    const int lane = t & 63, nfl = t >> 6;
    const int r = lane & 15, q = lane >> 4;
    const int nl = nfl * 16 + r;
    u16x8 vh, vl;
#pragma unroll
    for (int j = 0; j < 8; ++j) {
        float v = tile[q * 8 + j][nl];
        u16 h = f2b(v);
        vh[j] = h;
        vl[j] = f2b(v - b2f(h));
    }
    const int KS = K >> 5;
    const size_t nf  = (size_t)(n0 >> 4) + nfl;
    const size_t off = (nf * KS + (k0 >> 5)) * 512 + lane * 8;
    *(u16x8*)(Dh + off) = vh;
    *(u16x8*)(Dl + off) = vl;
}

__global__ __launch_bounds__(256) void pack_z(const float* __restrict__ z0,
                                              float* __restrict__ Zf,
                                              u16* __restrict__ Zh, u16* __restrict__ Zl) {
    const int gid  = blockIdx.x * 256 + threadIdx.x;  // 65536 total
    const int lane = gid & 63;
    const int cidx = gid >> 6;                        // 0..1023
    const int ks = cidx & 31;
    const int mf = cidx >> 5;                         // 0..31
    const int r = lane & 15, q = lane >> 4;
    const int row = mf * 16 + r;
    const int col = ks * 32 + q * 8;
    const float* src = z0 + (size_t)row * DIM + col;
    f32x4 a = *(const f32x4*)src;
    f32x4 b = *(const f32x4*)(src + 4);
    u16x8 vh, vl;
#pragma unroll
    for (int j = 0; j < 4; ++j) {
        u16 h = f2b(a[j]); vh[j] = h; vl[j] = f2b(a[j] - b2f(h));
        u16 h2 = f2b(b[j]); vh[4 + j] = h2; vl[4 + j] = f2b(b[j] - b2f(h2));
    }
    *(f32x4*)(Zf + (size_t)row * DIM + col)     = a;
    *(f32x4*)(Zf + (size_t)row * DIM + col + 4) = b;
    const size_t off = ((size_t)mf * 32 + ks) * 512 + lane * 8;
    *(u16x8*)(Zh + off) = vh;
    *(u16x8*)(Zl + off) = vl;
}

// ---------------- 4-wave, 4-deep-pipelined LDS-staged GEMM ----------------
// Block: 256 thr / 4 waves (2x2). Tile: (MFT*16) x (NFT*16). Wave tile:
// (MFT/2*16) x (NFT/2*16). K-loop: 4 LDS buffers, prefetch distance 3;
// each wave stages CPW=NCH/4 chunks via global_load_lds; counted per-wave
// vmcnt (3,2,1,0 x CPW peeled tail); raw s_barriers.
// EPI 1: H = tanh(acc+bias+ti*wt) -> Oh/Ol A-frag-packed ([mf][KSo][512])
// EPI 2: zn = Zin + hseg*(acc+bias) -> Fout f32 row-major (+ packed Oh/Ol)
template <int MFT, int NFT, int KSc, int KSo, int EPI>
__global__ __launch_bounds__(256) void gemm_mw(
    const u16* __restrict__ Ah, const u16* __restrict__ Al,
    const u16* __restrict__ Bh, const u16* __restrict__ Bl,
    const float* __restrict__ bias, const float* __restrict__ wvec,
    const float* __restrict__ t, int step,
    const float* __restrict__ Zin, float* __restrict__ Fout,
    u16* __restrict__ Oh, u16* __restrict__ Ol, int wsplit) {

    constexpr int NCH = (MFT + NFT) * 2;      // chunks per K-step (A hi/lo + B hi/lo)
    constexpr int CPW = NCH / 4;              // chunks staged per wave
    constexpr int MFW = MFT / 2, NFW = NFT / 2;
    __shared__ __align__(16) u16 sb[4][NCH][512];   // 4-deep staging ring

    const int tid = threadIdx.x;
    const int l   = tid & 63;
    const int w   = tid >> 6;                 // wave 0..3
    const int wm  = w >> 1, wn = w & 1;

    const int nwg = gridDim.x;
    const int bid = blockIdx.x;
    const int swz = (bid & 7) * (nwg >> 3) + (bid >> 3);  // bijective XCD swizzle
    constexpr int BM = BS / (MFT * 16);
    const int bm = swz % BM;
    const int bn = swz / BM;

    const u16* pAh = Ah + ((size_t)(bm * MFT) * KSc) * 512 + l * 8;
    const u16* pAl = Al + ((size_t)(bm * MFT) * KSc) * 512 + l * 8;
    const u16* pBh = Bh + ((size_t)(bn * NFT) * KSc) * 512 + l * 8;
    const u16* pBl = Bl + ((size_t)(bn * NFT) * KSc) * 512 + l * 8;

    // per-wave staging sources (this wave's CPW chunks of each K-step)
    const u16* csrc[CPW];
#pragma unroll
    for (int i = 0; i < CPW; ++i) {
        const int c = w * CPW + i;
        const u16* s;
        if      (c < MFT)           s = pAh + (size_t)c * KSc * 512;
        else if (c < 2 * MFT)       s = pAl + (size_t)(c - MFT) * KSc * 512;
        else if (c < 2 * MFT + NFT) s = pBh + (size_t)(c - 2 * MFT) * KSc * 512;
        else                        s = pBl + (size_t)(c - 2 * MFT - NFT) * KSc * 512;
        csrc[i] = s;
    }

    // time-step scalars
    const int   seg  = step >> 1, sub = step & 1;
    const float t0   = t[seg], t1 = t[seg + 1];
    const float hseg = 0.5f * (t1 - t0);
    const float ti   = t0 + hseg * (float)sub;

    f32x4 acc[MFW][NFW] = {};

    auto STAGE = [&](int k, int nb) {
        u16* dst = &sb[0][0][0] + ((size_t)nb * NCH + w * CPW) * 512;
#pragma unroll
        for (int i = 0; i < CPW; ++i)
            glds16(csrc[i] + (size_t)k * 512, dst + i * 512);
    };

    auto COMPUTE = [&](int cur) {
        const u16* base = &sb[cur][0][0];
        u16x8 ah[MFW], al[MFW], bh[NFW], bl[NFW];
#pragma unroll
        for (int mi = 0; mi < MFW; ++mi) {
            ah[mi] = *(const u16x8*)(base + (size_t)(wm * MFW + mi) * 512 + l * 8);
            al[mi] = *(const u16x8*)(base + (size_t)(MFT + wm * MFW + mi) * 512 + l * 8);
        }
#pragma unroll
        for (int ni = 0; ni < NFW; ++ni) {
            bh[ni] = *(const u16x8*)(base + (size_t)(2 * MFT + wn * NFW + ni) * 512 + l * 8);
            bl[ni] = *(const u16x8*)(base + (size_t)(2 * MFT + NFT + wn * NFW + ni) * 512 + l * 8);
        }
#pragma unroll
        for (int mi = 0; mi < MFW; ++mi)
#pragma unroll
            for (int ni = 0; ni < NFW; ++ni) {
                acc[mi][ni] = MFMA16(ah[mi], bh[ni], acc[mi][ni]);
                acc[mi][ni] = MFMA16(ah[mi], bl[ni], acc[mi][ni]);
                acc[mi][ni] = MFMA16(al[mi], bh[ni], acc[mi][ni]);
            }
    };

    asm volatile("s_waitcnt vmcnt(0) lgkmcnt(0)" ::: "memory");
    STAGE(0, 0);
    STAGE(1, 1);
    STAGE(2, 2);
    for (int k = 0; k < KSc - 3; ++k) {
        STAGE(k + 3, (k + 3) & 3);                          // 3 tiles in flight
        asm volatile("s_waitcnt vmcnt(%0)" :: "i"(3 * CPW) : "memory");  // k's loads done
        __builtin_amdgcn_s_barrier();                       // all waves: buf[k] ready
        COMPUTE(k & 3);
        __builtin_amdgcn_s_barrier();                       // buf[k] free for overwrite
    }
    // peeled tail: exact counted drains (no new stages)
    asm volatile("s_waitcnt vmcnt(%0)" :: "i"(2 * CPW) : "memory");
    __builtin_amdgcn_s_barrier();
    COMPUTE((KSc - 3) & 3);
    __builtin_amdgcn_s_barrier();
    asm volatile("s_waitcnt vmcnt(%0)" :: "i"(1 * CPW) : "memory");
    __builtin_amdgcn_s_barrier();
    COMPUTE((KSc - 2) & 3);
    __builtin_amdgcn_s_barrier();
    asm volatile("s_waitcnt vmcnt(0)" ::: "memory");
    __builtin_amdgcn_s_barrier();
    COMPUTE((KSc - 1) & 3);
    __syncthreads();                                        // full drain before LDS reuse

    // ---- epilogue: transpose C-frags through reused LDS ----
    float* epi = reinterpret_cast<float*>(&sb[0][0][0]);    // [MFT*16][EW]
    constexpr int EW = NFT * 16 + 4;
    const int r = l & 15, q = l >> 4;
#pragma unroll
    for (int mi = 0; mi < MFW; ++mi)
#pragma unroll
        for (int ni = 0; ni < NFW; ++ni)
#pragma unroll
            for (int j = 0; j < 4; ++j)
                epi[(wm * MFW * 16 + mi * 16 + q * 4 + j) * EW
                    + wn * NFW * 16 + ni * 16 + r] = acc[mi][ni][j];
    __syncthreads();

    constexpr int PPW = (MFT * (NFT / 2)) / 4;   // (row-slice, col-chunk) pairs per wave
#pragma unroll
    for (int pi = 0; pi < PPW; ++pi) {
        const int p  = w * PPW + pi;
        const int rs = p / (NFT / 2);
        const int kc = p % (NFT / 2);
        const int c0 = bn * (NFT * 16) + kc * 32 + q * 8;   // global col base for lane
        f32x4 v0 = *(const f32x4*)&epi[(rs * 16 + r) * EW + kc * 32 + q * 8];
        f32x4 v1 = *(const f32x4*)&epi[(rs * 16 + r) * EW + kc * 32 + q * 8 + 4];
        float v[8];
#pragma unroll
        for (int j = 0; j < 4; ++j) { v[j] = v0[j]; v[4 + j] = v1[j]; }

        const int    mfg = bm * MFT + rs;
        const int    kch = bn * (NFT / 2) + kc;
        const size_t off = ((size_t)mfg * KSo + kch) * 512 + l * 8;

        if constexpr (EPI == 1) {
            u16x8 vh, vl;
#pragma unroll
            for (int j = 0; j < 8; ++j) {
                float u  = v[j] + bias[c0 + j] + ti * wvec[c0 + j];
                float tv = fast_tanh(u);
                u16 hb = f2b(tv);
                vh[j] = hb;
                vl[j] = f2b(tv - b2f(hb));
            }
            *(u16x8*)(Oh + off) = vh;
            *(u16x8*)(Ol + off) = vl;
        } else {
            constexpr int NT = KSo * 32;               // output row length
            const int    rg  = bm * (MFT * 16) + rs * 16 + r;
            const float* zp  = Zin + (size_t)rg * NT + c0;
            f32x4 z0v = *(const f32x4*)zp;
            f32x4 z1v = *(const f32x4*)(zp + 4);
            float zn[8];
#pragma unroll
            for (int j = 0; j < 8; ++j) {
                float f  = v[j] + bias[c0 + j];
                float zi = (j < 4) ? z0v[j] : z1v[j - 4];
                zn[j] = zi + hseg * f;
            }
            f32x4 o0, o1;
#pragma unroll
            for (int j = 0; j < 4; ++j) { o0[j] = zn[j]; o1[j] = zn[4 + j]; }
            *(f32x4*)(Fout + (size_t)rg * NT + c0)     = o0;
            *(f32x4*)(Fout + (size_t)rg * NT + c0 + 4) = o1;
            if (wsplit) {
                u16x8 vh, vl;
#pragma unroll
                for (int j = 0; j < 8; ++j) {
                    u16 hb = f2b(zn[j]);
                    vh[j] = hb;
                    vl[j] = f2b(zn[j] - b2f(hb));
                }
                *(u16x8*)(Oh + off) = vh;
                *(u16x8*)(Ol + off) = vl;
            }
        }
    }
}

// ---------------- launch ----------------
extern "C" void kernel_launch(void* const* d_in, const int* in_sizes, int n_in,
                              void* d_out, int out_size, void* d_ws, size_t ws_size,
                              hipStream_t stream) {
    const float* z0 = (const float*)d_in[0];
    const float* t  = (const float*)d_in[1];
    const float* W1 = (const float*)d_in[2];
    const float* b1 = (const float*)d_in[3];
    const float* wt = (const float*)d_in[4];
    const float* W2 = (const float*)d_in[5];
    const float* b2 = (const float*)d_in[6];

    char* ws = (char*)d_ws;
    float* Zf  = (float*)(ws);                    // 2 MB   512x1024 f32
    u16*   Zh  = (u16*)(ws + (2u  << 20));        // 1 MB   packed [32][32][512]
    u16*   Zl  = (u16*)(ws + (3u  << 20));        // 1 MB
    u16*   Hh  = (u16*)(ws + (4u  << 20));        // 2 MB   packed [32][64][512]
    u16*   Hl  = (u16*)(ws + (6u  << 20));        // 2 MB
    u16*   W1h = (u16*)(ws + (8u  << 20));        // 4 MB   packed [128][32][512]
    u16*   W1l = (u16*)(ws + (12u << 20));        // 4 MB
    u16*   W2h = (u16*)(ws + (16u << 20));        // 4 MB   packed [64][64][512]
    u16*   W2l = (u16*)(ws + (20u << 20));        // 4 MB

    pack_w<<<dim3(HID / 64, DIM / 32), 256, 0, stream>>>(W1, DIM, HID, W1h, W1l);
    pack_w<<<dim3(DIM / 64, HID / 32), 256, 0, stream>>>(W2, HID, DIM, W2h, W2l);
    pack_z<<<256, 256, 0, stream>>>(z0, Zf, Zh, Zl);

    float* out = (float*)d_out;
    for (int step = 0; step < NSTEPS; ++step) {
        // H = tanh(Z @ W1 + b1 + ti*wt)   (512x2048, K=1024): 64x64 tiles, grid 256
        gemm_mw<4, 4, 32, 64, 1><<<256, 256, 0, stream>>>(
            Zh, Zl, W1h, W1l, b1, wt, t, step,
            nullptr, nullptr, Hh, Hl, 1);
        // Znew = Z + h*(H @ W2 + b2)      (512x1024, K=2048): 32x64 tiles, grid 256
        const bool last = (step == NSTEPS - 1);
        gemm_mw<2, 4, 64, 32, 2><<<256, 256, 0, stream>>>(
            Hh, Hl, W2h, W2l, b2, nullptr, t, step,
            Zf, last ? out : Zf, Zh, Zl, last ? 0 : 1);
    }
}